// Round 1
// baseline (803.662 us; speedup 1.0000x reference)
//
#include <hip/hip_runtime.h>
#include <math.h>

// Problem constants (B, N, L, D) from the reference setup_inputs().
#define BSZ 64
#define NN  128
#define LL  64
#define DD  768
#define KC  16
#define NEGV (-9e9f)

// ---------------------------------------------------------------------------
// Kernel 1: one block per (i, j) pair.
//   - fp32 register-tiled GEMM: C[128][64] = text[i] (128x768) @ image[j]^T (64x768)
//   - apply mask -> NEG, stage tile in LDS
//   - row softmax (over l) -> score1 contribution; col softmax (over n) -> score2
//   - S[i,j] = (sum_n row + sum_l col) / N
//   - diagonal blocks additionally write softmax weights W[b][l][n] to workspace
// ---------------------------------------------------------------------------
__global__ __launch_bounds__(256) void k_scores(
    const float* __restrict__ text, const float* __restrict__ img,
    const int* __restrict__ tmask, const int* __restrict__ imask,
    float* __restrict__ S, float* __restrict__ W)
{
    __shared__ float As[KC][NN];       // 8 KB, k-major
    __shared__ float Bs2[KC][LL];      // 4 KB, k-major
    __shared__ float Cs[NN][LL + 1];   // 33.3 KB, padded (+1) for reductions
    __shared__ float tmi[NN];
    __shared__ float imj[LL];
    __shared__ float rowred[NN];
    __shared__ float colred[LL];

    const int i = blockIdx.y, j = blockIdx.x;
    const int tid = threadIdx.x;
    const int tx = tid & 15;          // 0..15 -> columns l = tx*4..+3
    const int ty = tid >> 4;          // 0..15 -> rows    n = ty*8..+7

    float acc[8][4];
#pragma unroll
    for (int r = 0; r < 8; r++)
#pragma unroll
        for (int c = 0; c < 4; c++) acc[r][c] = 0.f;

    const float* Ab = text + (size_t)i * NN * DD;
    const float* Bb = img  + (size_t)j * LL * DD;

    if (tid < NN) tmi[tid] = tmask[i * NN + tid] ? 1.f : 0.f;
    if (tid < LL) imj[tid] = imask[j * LL + tid] ? 1.f : 0.f;

    // staging assignments
    const int an = tid >> 1;          // 0..127 (A row)
    const int ak = (tid & 1) * 8;     // k offset 0 or 8 (8 floats each)
    const int bl = tid >> 2;          // 0..63  (B row)
    const int bk = (tid & 3) * 4;     // k offset 0,4,8,12 (4 floats)

    for (int k0 = 0; k0 < DD; k0 += KC) {
        float4 a0 = *(const float4*)(Ab + (size_t)an * DD + k0 + ak);
        float4 a1 = *(const float4*)(Ab + (size_t)an * DD + k0 + ak + 4);
        float4 b0 = *(const float4*)(Bb + (size_t)bl * DD + k0 + bk);
        __syncthreads();   // previous iteration's LDS reads done before overwrite
        As[ak + 0][an] = a0.x; As[ak + 1][an] = a0.y;
        As[ak + 2][an] = a0.z; As[ak + 3][an] = a0.w;
        As[ak + 4][an] = a1.x; As[ak + 5][an] = a1.y;
        As[ak + 6][an] = a1.z; As[ak + 7][an] = a1.w;
        Bs2[bk + 0][bl] = b0.x; Bs2[bk + 1][bl] = b0.y;
        Bs2[bk + 2][bl] = b0.z; Bs2[bk + 3][bl] = b0.w;
        __syncthreads();
#pragma unroll
        for (int kk = 0; kk < KC; kk++) {
            float4 av0 = *(const float4*)&As[kk][ty * 8];
            float4 av1 = *(const float4*)&As[kk][ty * 8 + 4];
            float4 bv  = *(const float4*)&Bs2[kk][tx * 4];
            float a[8] = {av0.x, av0.y, av0.z, av0.w, av1.x, av1.y, av1.z, av1.w};
            float b[4] = {bv.x, bv.y, bv.z, bv.w};
#pragma unroll
            for (int r = 0; r < 8; r++)
#pragma unroll
                for (int c = 0; c < 4; c++)
                    acc[r][c] = fmaf(a[r], b[c], acc[r][c]);
        }
    }
    __syncthreads();

    // masked att -> LDS tile.  att = (mask && dot != 0) ? dot : NEG
#pragma unroll
    for (int r = 0; r < 8; r++) {
        int n = ty * 8 + r;
        float tv = tmi[n];
#pragma unroll
        for (int c = 0; c < 4; c++) {
            int l = tx * 4 + c;
            float v = acc[r][c];
            bool keep = (tv != 0.f) && (imj[l] != 0.f) && (v != 0.f);
            Cs[n][l] = keep ? v : NEGV;
        }
    }
    __syncthreads();

    // score1: softmax over l for each row n (threads 0..127)
    if (tid < NN) {
        const int n = tid;
        float m = -INFINITY;
        for (int l = 0; l < LL; l++) m = fmaxf(m, Cs[n][l]);
        float s = 0.f, ws = 0.f;
        for (int l = 0; l < LL; l++) {
            float v = Cs[n][l];
            float e = __expf(v - m);     // all-NEG row -> e = 1 (uniform)
            s += e;
            ws += imj[l] * e * v;        // e==0 underflow makes masked terms exact 0
        }
        rowred[n] = tmi[n] * (ws / s);
    } else if (tid < NN + LL) {
        // score2: softmax over n for each column l (threads 128..191)
        const int l = tid - NN;
        float m = -INFINITY;
        for (int n = 0; n < NN; n++) m = fmaxf(m, Cs[n][l]);
        float s = 0.f, ws = 0.f;
        for (int n = 0; n < NN; n++) {
            float v = Cs[n][l];
            float e = __expf(v - m);
            s += e;
            ws += tmi[n] * e * v;
        }
        colred[l] = imj[l] * (ws / s);
    }
    __syncthreads();

    if (tid < 64) {
        float p = rowred[tid] + rowred[tid + 64] + colred[tid];
#pragma unroll
        for (int off = 32; off; off >>= 1) p += __shfl_down(p, off);
        if (tid == 0) S[i * BSZ + j] = p / (float)NN;
    }

    // diagonal blocks: write unmasked row-softmax weights W[b][l][n] (transposed)
    if (i == j) {
        if (tid < NN) {
            const int n = tid;
            float m = -INFINITY;
            for (int l = 0; l < LL; l++) m = fmaxf(m, Cs[n][l]);
            float s = 0.f;
            for (int l = 0; l < LL; l++) s += __expf(Cs[n][l] - m);
            float inv = 1.f / s;
            float* Wb = W + (size_t)i * LL * NN;
            for (int l = 0; l < LL; l++)
                Wb[(size_t)l * NN + n] = __expf(Cs[n][l] - m) * inv;  // coalesced over n
        }
    }
}

// ---------------------------------------------------------------------------
// Kernel 2: text_emb_i2s[b,n,d] = sum_l W[b][l][n] * img[b][l][d]
// Grid: (64 b, 3 d-chunks of 256). W reads are lane-uniform (scalarizable).
// ---------------------------------------------------------------------------
__global__ __launch_bounds__(256) void k_i2s(
    const float* __restrict__ W, const float* __restrict__ img,
    float* __restrict__ out)
{
    const int b = blockIdx.x;
    const int d = blockIdx.y * 256 + threadIdx.x;
    const float* Wb = W  + (size_t)b * LL * NN;
    const float* ib = img + (size_t)b * LL * DD;
    float* ob = out + 1 + (size_t)b * NN * DD;   // slot 0 of d_out is the loss

    for (int ng = 0; ng < NN; ng += 16) {
        float acc[16];
#pragma unroll
        for (int q = 0; q < 16; q++) acc[q] = 0.f;
        for (int l = 0; l < LL; l++) {
            float g = ib[(size_t)l * DD + d];
#pragma unroll
            for (int q = 0; q < 16; q++)
                acc[q] = fmaf(Wb[(size_t)l * NN + ng + q], g, acc[q]);
        }
#pragma unroll
        for (int q = 0; q < 16; q++)
            ob[(size_t)(ng + q) * DD + d] = acc[q];
    }
}

// ---------------------------------------------------------------------------
// Kernel 3: loss = -sum_i( 2*S[i,i] - lse_row_i(S) - lse_col_i(S) ) / B
// One wave; thread i handles row i and column i.
// ---------------------------------------------------------------------------
__global__ void k_loss(const float* __restrict__ S, float* __restrict__ out)
{
    const int t = threadIdx.x;  // 0..63
    float diag = S[t * BSZ + t];
    float m1 = -INFINITY, m2 = -INFINITY;
    for (int jj = 0; jj < BSZ; jj++) {
        m1 = fmaxf(m1, S[t * BSZ + jj]);
        m2 = fmaxf(m2, S[jj * BSZ + t]);
    }
    float s1 = 0.f, s2 = 0.f;
    for (int jj = 0; jj < BSZ; jj++) {
        s1 += __expf(S[t * BSZ + jj] - m1);
        s2 += __expf(S[jj * BSZ + t] - m2);
    }
    float p = 2.f * diag - (m1 + logf(s1)) - (m2 + logf(s2));
#pragma unroll
    for (int off = 32; off; off >>= 1) p += __shfl_down(p, off);
    if (t == 0) out[0] = -p / (float)BSZ;
}

// ---------------------------------------------------------------------------
extern "C" void kernel_launch(void* const* d_in, const int* in_sizes, int n_in,
                              void* d_out, int out_size, void* d_ws, size_t ws_size,
                              hipStream_t stream)
{
    (void)in_sizes; (void)n_in; (void)out_size; (void)ws_size;
    const float* text = (const float*)d_in[0];   // [64,128,768] fp32
    const float* img  = (const float*)d_in[1];   // [64, 64,768] fp32
    const int*   tm   = (const int*)d_in[2];     // [64,128] int32
    const int*   im   = (const int*)d_in[3];     // [64, 64] int32
    float* out = (float*)d_out;                  // [1 + 64*128*768] fp32

    float* S = (float*)d_ws;                     // 64*64
    float* W = S + BSZ * BSZ;                    // 64*64*128 (layout [b][l][n])

    dim3 g1(BSZ, BSZ);
    k_scores<<<g1, 256, 0, stream>>>(text, img, tm, im, S, W);
    dim3 g2(BSZ, 3);
    k_i2s<<<g2, 256, 0, stream>>>(W, img, out);
    k_loss<<<1, 64, 0, stream>>>(S, out);
}

// Round 2
// 620.123 us; speedup vs baseline: 1.2960x; 1.2960x over previous
//
#include <hip/hip_runtime.h>
#include <math.h>

// Problem constants (B, N, L, D) from the reference setup_inputs().
#define BSZ 64
#define NN  128
#define LL  64
#define DD  768
#define NEGV (-9e9f)

#define TQ (BSZ * NN * DD / 4)   // text float4 count  = 1572864
#define IQ (BSZ * LL * DD / 4)   // image float4 count =  786432

typedef __attribute__((ext_vector_type(8))) short bf16x8;  // 8 bf16 = 4 VGPRs
typedef __attribute__((ext_vector_type(4))) float f32x4;   // MFMA 16x16 accum

// round-to-nearest-even fp32 -> bf16 (bits in low 16)
__device__ __forceinline__ unsigned bf16r(float f) {
    unsigned u = __builtin_bit_cast(unsigned, f);
    return (u + 0x7fffu + ((u >> 16) & 1u)) >> 16;
}

// ---------------------------------------------------------------------------
// Kernel 0: split fp32 -> (hi, lo) bf16 pairs.  x ~= hi + lo, |lo| <~ 2^-9|x|.
// One thread per float4.  Exact grid: (TQ + IQ) / 256 blocks.
// ---------------------------------------------------------------------------
__global__ __launch_bounds__(256) void k_prep(
    const float4* __restrict__ t4, const float4* __restrict__ g4,
    uint2* __restrict__ Ahi, uint2* __restrict__ Alo,
    uint2* __restrict__ Bhi, uint2* __restrict__ Blo)
{
    int id = blockIdx.x * 256 + threadIdx.x;
    const float4* src; uint2 *dh, *dl; int idx;
    if (id < TQ) { src = t4; dh = Ahi; dl = Alo; idx = id; }
    else         { src = g4; dh = Bhi; dl = Blo; idx = id - TQ; }
    float4 x = src[idx];
    unsigned h0 = bf16r(x.x), h1 = bf16r(x.y), h2 = bf16r(x.z), h3 = bf16r(x.w);
    float f0 = __builtin_bit_cast(float, h0 << 16);
    float f1 = __builtin_bit_cast(float, h1 << 16);
    float f2 = __builtin_bit_cast(float, h2 << 16);
    float f3 = __builtin_bit_cast(float, h3 << 16);
    unsigned l0 = bf16r(x.x - f0), l1 = bf16r(x.y - f1);
    unsigned l2 = bf16r(x.z - f2), l3 = bf16r(x.w - f3);
    dh[idx] = make_uint2(h0 | (h1 << 16), h2 | (h3 << 16));
    dl[idx] = make_uint2(l0 | (l1 << 16), l2 | (l3 << 16));
}

// ---------------------------------------------------------------------------
// Kernel 1: one block per (i, j) pair (8x8 group swizzle for L2 locality).
// Split-bf16 MFMA GEMM: C[128][64] = text[i] @ image[j]^T via
// 16x16x32 bf16 MFMA, fragments loaded directly from global (no staging LDS).
// Then masked softmax reductions identical to the verified fp32 version.
// ---------------------------------------------------------------------------
__global__ __launch_bounds__(256) void k_scores(
    const unsigned short* __restrict__ Ahi, const unsigned short* __restrict__ Alo,
    const unsigned short* __restrict__ Bhi, const unsigned short* __restrict__ Blo,
    const int* __restrict__ tmask, const int* __restrict__ imask,
    float* __restrict__ S, float* __restrict__ W)
{
    __shared__ float Cs[NN][LL + 1];   // 33.3 KB, +1 pad for reductions
    __shared__ float tmi[NN];
    __shared__ float imj[LL];
    __shared__ float rowred[NN];
    __shared__ float colred[LL];

    // swizzle: 8x8 groups of 8x8 blocks -> 4.7 MB working set per group
    const int bid = blockIdx.x;
    const int group = bid >> 6, idx = bid & 63;
    const int i = (group >> 3) * 8 + (idx >> 3);
    const int j = (group & 7) * 8 + (idx & 7);

    const int tid  = threadIdx.x;
    const int wave = tid >> 6;
    const int lane = tid & 63;
    const int quad = lane >> 4;
    const int l15  = lane & 15;

    if (tid < NN) tmi[tid] = tmask[i * NN + tid] ? 1.f : 0.f;
    if (tid < LL) imj[tid] = imask[j * LL + tid] ? 1.f : 0.f;

    // fragment base pointers: A[m=l15][k=quad*8+jj], same pattern for B (B^T gemm)
    const size_t koff = (size_t)quad * 8;
    const unsigned short* pAh0 = Ahi + (size_t)i * NN * DD + (size_t)(wave * 32 + l15) * DD + koff;
    const unsigned short* pAh1 = pAh0 + (size_t)16 * DD;
    const unsigned short* pAl0 = Alo + (pAh0 - Ahi);
    const unsigned short* pAl1 = pAl0 + (size_t)16 * DD;
    const unsigned short* pBh  = Bhi + (size_t)j * LL * DD + (size_t)l15 * DD + koff;
    const unsigned short* pBl  = Blo + (pBh - Bhi);

    f32x4 acc[2][4];
    const f32x4 zf = {0.f, 0.f, 0.f, 0.f};
#pragma unroll
    for (int tr = 0; tr < 2; tr++)
#pragma unroll
        for (int tc = 0; tc < 4; tc++) acc[tr][tc] = zf;

    for (int k0 = 0; k0 < DD; k0 += 32) {
        bf16x8 ah0 = *(const bf16x8*)(pAh0 + k0);
        bf16x8 ah1 = *(const bf16x8*)(pAh1 + k0);
        bf16x8 al0 = *(const bf16x8*)(pAl0 + k0);
        bf16x8 al1 = *(const bf16x8*)(pAl1 + k0);
#pragma unroll
        for (int tc = 0; tc < 4; tc++) {
            bf16x8 bh = *(const bf16x8*)(pBh + (size_t)tc * 16 * DD + k0);
            bf16x8 bl = *(const bf16x8*)(pBl + (size_t)tc * 16 * DD + k0);
            acc[0][tc] = __builtin_amdgcn_mfma_f32_16x16x32_bf16(ah0, bh, acc[0][tc], 0, 0, 0);
            acc[1][tc] = __builtin_amdgcn_mfma_f32_16x16x32_bf16(ah1, bh, acc[1][tc], 0, 0, 0);
            acc[0][tc] = __builtin_amdgcn_mfma_f32_16x16x32_bf16(al0, bh, acc[0][tc], 0, 0, 0);
            acc[1][tc] = __builtin_amdgcn_mfma_f32_16x16x32_bf16(al1, bh, acc[1][tc], 0, 0, 0);
            acc[0][tc] = __builtin_amdgcn_mfma_f32_16x16x32_bf16(ah0, bl, acc[0][tc], 0, 0, 0);
            acc[1][tc] = __builtin_amdgcn_mfma_f32_16x16x32_bf16(ah1, bl, acc[1][tc], 0, 0, 0);
        }
    }
    __syncthreads();   // tmi/imj visible to all; Cs not yet touched

    // masked att -> LDS tile.  att = (mask && dot != 0) ? dot : NEG
    // C/D layout: row = quad*4 + reg, col = l15 (per-tile)
#pragma unroll
    for (int tr = 0; tr < 2; tr++) {
        int rb = wave * 32 + tr * 16 + quad * 4;
#pragma unroll
        for (int tc = 0; tc < 4; tc++) {
            int col = tc * 16 + l15;
            float im = imj[col];
#pragma unroll
            for (int r = 0; r < 4; r++) {
                int row = rb + r;
                float v = acc[tr][tc][r];
                bool keep = (tmi[row] != 0.f) && (im != 0.f) && (v != 0.f);
                Cs[row][col] = keep ? v : NEGV;
            }
        }
    }
    __syncthreads();

    // score1: softmax over l for each row n (threads 0..127)
    if (tid < NN) {
        const int n = tid;
        float m = -INFINITY;
        for (int l = 0; l < LL; l++) m = fmaxf(m, Cs[n][l]);
        float s = 0.f, ws = 0.f;
        for (int l = 0; l < LL; l++) {
            float v = Cs[n][l];
            float e = __expf(v - m);     // all-NEG row -> e = 1 (uniform)
            s += e;
            ws += imj[l] * e * v;        // e==0 underflow zeroes masked terms
        }
        rowred[n] = tmi[n] * (ws / s);
    } else if (tid < NN + LL) {
        // score2: softmax over n for each column l (threads 128..191)
        const int l = tid - NN;
        float m = -INFINITY;
        for (int n = 0; n < NN; n++) m = fmaxf(m, Cs[n][l]);
        float s = 0.f, ws = 0.f;
        for (int n = 0; n < NN; n++) {
            float v = Cs[n][l];
            float e = __expf(v - m);
            s += e;
            ws += tmi[n] * e * v;
        }
        colred[l] = imj[l] * (ws / s);
    }
    __syncthreads();

    if (tid < 64) {
        float p = rowred[tid] + rowred[tid + 64] + colred[tid];
#pragma unroll
        for (int off = 32; off; off >>= 1) p += __shfl_down(p, off);
        if (tid == 0) S[i * BSZ + j] = p / (float)NN;
    }

    // diagonal blocks: write unmasked row-softmax weights W[b][l][n] (transposed)
    if (i == j) {
        if (tid < NN) {
            const int n = tid;
            float m = -INFINITY;
            for (int l = 0; l < LL; l++) m = fmaxf(m, Cs[n][l]);
            float s = 0.f;
            for (int l = 0; l < LL; l++) s += __expf(Cs[n][l] - m);
            float inv = 1.f / s;
            float* Wb = W + (size_t)i * LL * NN;
            for (int l = 0; l < LL; l++)
                Wb[(size_t)l * NN + n] = __expf(Cs[n][l] - m) * inv;  // coalesced over n
        }
    }
}

// ---------------------------------------------------------------------------
// Kernel 2: text_emb_i2s[b,n,d] = sum_l W[b][l][n] * img[b][l][d]
// Grid: (64 b, 3 d-chunks of 256, 8 n-groups of 16).  W chunk staged in LDS.
// ---------------------------------------------------------------------------
__global__ __launch_bounds__(256) void k_i2s(
    const float* __restrict__ W, const float* __restrict__ img,
    float* __restrict__ out)
{
    __shared__ float Ws[LL][16];   // 4 KB
    const int b  = blockIdx.x;
    const int ng = blockIdx.z * 16;
    const int d  = blockIdx.y * 256 + threadIdx.x;
    const float* Wb = W + (size_t)b * LL * NN;

    {   // stage W[l][ng..ng+15]: 1024 floats, 4 per thread
        int t4 = threadIdx.x * 4;
        int l = t4 >> 4, noff = t4 & 15;
        float4 w = *(const float4*)(Wb + (size_t)l * NN + ng + noff);
        Ws[l][noff + 0] = w.x; Ws[l][noff + 1] = w.y;
        Ws[l][noff + 2] = w.z; Ws[l][noff + 3] = w.w;
    }
    __syncthreads();

    const float* ib = img + (size_t)b * LL * DD;
    float* ob = out + 1 + (size_t)b * NN * DD + (size_t)ng * DD;  // slot 0 = loss

    float acc[16];
#pragma unroll
    for (int q = 0; q < 16; q++) acc[q] = 0.f;
    for (int l = 0; l < LL; l++) {
        float g = ib[(size_t)l * DD + d];
#pragma unroll
        for (int q = 0; q < 16; q++)
            acc[q] = fmaf(Ws[l][q], g, acc[q]);   // Ws read is broadcast
    }
#pragma unroll
    for (int q = 0; q < 16; q++)
        ob[(size_t)q * DD + d] = acc[q];
}

// ---------------------------------------------------------------------------
// Kernel 3: loss = -sum_i( 2*S[i,i] - lse_row_i(S) - lse_col_i(S) ) / B
// ---------------------------------------------------------------------------
__global__ void k_loss(const float* __restrict__ S, float* __restrict__ out)
{
    const int t = threadIdx.x;  // 0..63
    float diag = S[t * BSZ + t];
    float m1 = -INFINITY, m2 = -INFINITY;
    for (int jj = 0; jj < BSZ; jj++) {
        m1 = fmaxf(m1, S[t * BSZ + jj]);
        m2 = fmaxf(m2, S[jj * BSZ + t]);
    }
    float s1 = 0.f, s2 = 0.f;
    for (int jj = 0; jj < BSZ; jj++) {
        s1 += __expf(S[t * BSZ + jj] - m1);
        s2 += __expf(S[jj * BSZ + t] - m2);
    }
    float p = 2.f * diag - (m1 + logf(s1)) - (m2 + logf(s2));
#pragma unroll
    for (int off = 32; off; off >>= 1) p += __shfl_down(p, off);
    if (t == 0) out[0] = -p / (float)BSZ;
}

// ---------------------------------------------------------------------------
extern "C" void kernel_launch(void* const* d_in, const int* in_sizes, int n_in,
                              void* d_out, int out_size, void* d_ws, size_t ws_size,
                              hipStream_t stream)
{
    (void)in_sizes; (void)n_in; (void)out_size; (void)ws_size;
    const float* text = (const float*)d_in[0];   // [64,128,768] fp32
    const float* img  = (const float*)d_in[1];   // [64, 64,768] fp32
    const int*   tm   = (const int*)d_in[2];     // [64,128] int32
    const int*   im   = (const int*)d_in[3];     // [64, 64] int32
    float* out = (float*)d_out;                  // [1 + 64*128*768] fp32

    // workspace layout (bytes); total ~38 MB
    char* ws = (char*)d_ws;
    unsigned short* Ahi = (unsigned short*)(ws);                       // 12.58 MB
    unsigned short* Alo = (unsigned short*)(ws + 12582912);            // 12.58 MB
    unsigned short* Bhi = (unsigned short*)(ws + 25165824);            //  6.29 MB
    unsigned short* Blo = (unsigned short*)(ws + 31457280);            //  6.29 MB
    float* S = (float*)(ws + 37748736);                                // 16 KB
    float* W = (float*)(ws + 37765120);                                //  2 MB

    k_prep<<<(TQ + IQ) / 256, 256, 0, stream>>>(
        (const float4*)text, (const float4*)img,
        (uint2*)Ahi, (uint2*)Alo, (uint2*)Bhi, (uint2*)Blo);

    k_scores<<<BSZ * BSZ, 256, 0, stream>>>(Ahi, Alo, Bhi, Blo, tm, im, S, W);

    dim3 g2(BSZ, 3, 8);
    k_i2s<<<g2, 256, 0, stream>>>(W, img, out);

    k_loss<<<1, 64, 0, stream>>>(S, out);
}

// Round 3
// 289.800 us; speedup vs baseline: 2.7732x; 2.1398x over previous
//
#include <hip/hip_runtime.h>
#include <math.h>

// Problem constants (B, N, L, D) from the reference setup_inputs().
#define BSZ 64
#define NN  128
#define LL  64
#define DD  768
#define NEGV (-9e9f)

#define TQ (BSZ * NN * DD / 4)   // text float4 count  = 1572864
#define IQ (BSZ * LL * DD / 4)   // image float4 count =  786432

typedef __attribute__((ext_vector_type(8))) short bf16x8;  // 8 bf16 = 4 VGPRs
typedef __attribute__((ext_vector_type(4))) float f32x4;   // MFMA 16x16 accum

// round-to-nearest-even fp32 -> bf16 (bits in low 16)
__device__ __forceinline__ unsigned bf16r(float f) {
    unsigned u = __builtin_bit_cast(unsigned, f);
    return (u + 0x7fffu + ((u >> 16) & 1u)) >> 16;
}

// async 16B global -> LDS (dest = wave-uniform base + lane*16)
__device__ __forceinline__ void gl_lds16(const void* g, void* l) {
    __builtin_amdgcn_global_load_lds(
        (const __attribute__((address_space(1))) void*)g,
        (__attribute__((address_space(3))) void*)l, 16, 0, 0);
}

// ---------------------------------------------------------------------------
// Kernel 0: split fp32 -> (hi, lo) bf16 pairs.  x ~= hi + lo.
// ---------------------------------------------------------------------------
__global__ __launch_bounds__(256) void k_prep(
    const float4* __restrict__ t4, const float4* __restrict__ g4,
    uint2* __restrict__ Ahi, uint2* __restrict__ Alo,
    uint2* __restrict__ Bhi, uint2* __restrict__ Blo)
{
    int id = blockIdx.x * 256 + threadIdx.x;
    const float4* src; uint2 *dh, *dl; int idx;
    if (id < TQ) { src = t4; dh = Ahi; dl = Alo; idx = id; }
    else         { src = g4; dh = Bhi; dl = Blo; idx = id - TQ; }
    float4 x = src[idx];
    unsigned h0 = bf16r(x.x), h1 = bf16r(x.y), h2 = bf16r(x.z), h3 = bf16r(x.w);
    float f0 = __builtin_bit_cast(float, h0 << 16);
    float f1 = __builtin_bit_cast(float, h1 << 16);
    float f2 = __builtin_bit_cast(float, h2 << 16);
    float f3 = __builtin_bit_cast(float, h3 << 16);
    unsigned l0 = bf16r(x.x - f0), l1 = bf16r(x.y - f1);
    unsigned l2 = bf16r(x.z - f2), l3 = bf16r(x.w - f3);
    dh[idx] = make_uint2(h0 | (h1 << 16), h2 | (h3 << 16));
    dl[idx] = make_uint2(l0 | (l1 << 16), l2 | (l3 << 16));
}

// ---------------------------------------------------------------------------
// Stage one 32 KB chunk (A: 128 rows x 64 k bf16, B: 128 rows x 64 k) into LDS.
// LDS slot for (r, k8): r*8 + (k8 ^ (r&7)), 16B per slot (XOR bank swizzle).
// global_load_lds dest = wave-uniform base + lane*16, so slot index must be
// linear in (call, wave, lane) -- it is: slot = c*256 + wave*64 + lane.
// ---------------------------------------------------------------------------
__device__ __forceinline__ void stage_chunk(
    const unsigned short* __restrict__ pa, const unsigned short* __restrict__ pb,
    int k0, char* buf, int wave, int lane)
{
    int rsub = lane >> 3;     // 0..7
    int k8s  = lane & 7;
#pragma unroll
    for (int c = 0; c < 4; c++) {
        int r  = c * 32 + wave * 8 + rsub;
        int k8 = k8s ^ (r & 7);
        gl_lds16(pa + (size_t)r * DD + k0 + k8 * 8, buf + c * 4096 + wave * 1024);
        gl_lds16(pb + (size_t)r * DD + k0 + k8 * 8, buf + 16384 + c * 4096 + wave * 1024);
    }
}

// ---------------------------------------------------------------------------
// Kernel 1: one block per (i, jj) where jj covers j = {2jj, 2jj+1}.
// C[128][128] = text[i] @ [image[j0]; image[j1]]^T via split-bf16 MFMA
// (3 passes: ah*bh + ah*bl + al*bh), LDS-staged, double-buffered.
// Epilogue: masked softmax reductions (verified logic), S + diagonal W.
// ---------------------------------------------------------------------------
__global__ __launch_bounds__(256, 2) void k_scores(
    const unsigned short* __restrict__ Ahi, const unsigned short* __restrict__ Alo,
    const unsigned short* __restrict__ Bhi, const unsigned short* __restrict__ Blo,
    const int* __restrict__ tmask, const int* __restrict__ imask,
    float* __restrict__ S, float* __restrict__ W)
{
    union SmemU {
        char  stage[2][32768];     // [buf][A 16KB | B 16KB]
        float Cs[NN][129];         // 66 KB epilogue tile (stride 129: 2-way free)
    };
    __shared__ SmemU u;
    __shared__ float tmi[NN];
    __shared__ float imj[NN];      // 128 cols = two j's
    __shared__ float rowred[256];
    __shared__ float colred[NN];

    // 4x4 block-group swizzle for L2 locality (~3.2 MB working set / group)
    const int bid = blockIdx.x;
    const int grp = bid >> 4, idx = bid & 15;
    const int i  = (grp >> 3) * 4 + (idx >> 2);   // 0..63
    const int jj = (grp & 7) * 4 + (idx & 3);     // 0..31
    const int j0 = jj * 2;

    const int tid  = threadIdx.x;
    const int wave = tid >> 6;
    const int lane = tid & 63;
    const int quad = lane >> 4;
    const int l15  = lane & 15;
    const int rh   = wave & 1;     // row half (64 rows)
    const int ch   = wave >> 1;    // col half (64 cols)

    if (tid < NN) {
        tmi[tid] = tmask[i * NN + tid] ? 1.f : 0.f;
        imj[tid] = imask[j0 * LL + tid] ? 1.f : 0.f;   // two j's contiguous
    }

    const unsigned short* paHi = Ahi + (size_t)i * NN * DD;
    const unsigned short* paLo = Alo + (size_t)i * NN * DD;
    const unsigned short* pbHi = Bhi + (size_t)j0 * LL * DD;
    const unsigned short* pbLo = Blo + (size_t)j0 * LL * DD;

    f32x4 acc[4][4];
    const f32x4 zf = {0.f, 0.f, 0.f, 0.f};
#pragma unroll
    for (int tr = 0; tr < 4; tr++)
#pragma unroll
        for (int tc = 0; tc < 4; tc++) acc[tr][tc] = zf;

    // 36 chunks: pass 0 = ah*bh, pass 1 = ah*bl, pass 2 = al*bh; 12 k-chunks each
    stage_chunk(paHi, pbHi, 0, u.stage[0], wave, lane);
    __syncthreads();

    for (int c = 0; c < 36; c++) {
        int nc = c + 1;
        if (nc < 36) {
            int p = (nc >= 24) ? 2 : (nc >= 12 ? 1 : 0);
            const unsigned short* pa = (p == 2) ? paLo : paHi;
            const unsigned short* pb = (p == 1) ? pbLo : pbHi;
            stage_chunk(pa, pb, (nc - p * 12) << 6, u.stage[nc & 1], wave, lane);
        }
        const char* Ab = u.stage[c & 1];
        const char* Bb = Ab + 16384;
#pragma unroll
        for (int s = 0; s < 2; s++) {
            int k8q = s * 4 + quad;
            int sw  = k8q ^ (l15 & 7);
            bf16x8 af[4], bfr[4];
#pragma unroll
            for (int t = 0; t < 4; t++) {
                int row = rh * 64 + t * 16 + l15;
                af[t]  = *(const bf16x8*)(Ab + ((row << 3) + sw) * 16);
                int col = ch * 64 + t * 16 + l15;
                bfr[t] = *(const bf16x8*)(Bb + ((col << 3) + sw) * 16);
            }
#pragma unroll
            for (int tr = 0; tr < 4; tr++)
#pragma unroll
                for (int tc = 0; tc < 4; tc++)
                    acc[tr][tc] = __builtin_amdgcn_mfma_f32_16x16x32_bf16(
                        af[tr], bfr[tc], acc[tr][tc], 0, 0, 0);
        }
        __syncthreads();
    }

    // masked att -> Cs.  att = (mask && dot != 0) ? dot : NEG
    // C/D layout per 16x16 tile: row = quad*4 + rr, col = l15
#pragma unroll
    for (int tr = 0; tr < 4; tr++) {
        int rb = rh * 64 + tr * 16 + quad * 4;
#pragma unroll
        for (int tc = 0; tc < 4; tc++) {
            int col = ch * 64 + tc * 16 + l15;
            float im = imj[col];
#pragma unroll
            for (int rr = 0; rr < 4; rr++) {
                int row = rb + rr;
                float v = acc[tr][tc][rr];
                bool keep = (tmi[row] != 0.f) && (im != 0.f) && (v != 0.f);
                u.Cs[row][col] = keep ? v : NEGV;
            }
        }
    }
    __syncthreads();

    // phase 1: row softmax over l for each (jh, n) -- all 256 threads
    {
        int jh = tid >> 7, n = tid & 127;
        const float* Crow = &u.Cs[n][jh * 64];
        float m = -INFINITY;
        for (int l = 0; l < LL; l++) m = fmaxf(m, Crow[l]);
        float ssum = 0.f, ws = 0.f;
        for (int l = 0; l < LL; l++) {
            float v = Crow[l];
            float e = __expf(v - m);      // all-NEG row -> uniform
            ssum += e;
            ws += imj[jh * 64 + l] * e * v;
        }
        rowred[tid] = tmi[n] * (ws / ssum);
    }
    __syncthreads();

    // phase 2: threads 0..127 col softmax; threads 128..255 diagonal W
    if (tid < NN) {
        int jh = tid >> 6, l = tid & 63;
        float m = -INFINITY;
        for (int n = 0; n < NN; n++) m = fmaxf(m, u.Cs[n][jh * 64 + l]);
        float ssum = 0.f, ws = 0.f;
        for (int n = 0; n < NN; n++) {
            float v = u.Cs[n][jh * 64 + l];
            float e = __expf(v - m);
            ssum += e;
            ws += tmi[n] * e * v;
        }
        colred[tid] = imj[jh * 64 + l] * (ws / ssum);
    } else if (jj == (i >> 1)) {
        // this block holds the diagonal pair j == i at half jh = i & 1
        int jh = i & 1;
        int n = tid & 127;
        const float* Crow = &u.Cs[n][jh * 64];
        float m = -INFINITY;
        for (int l = 0; l < LL; l++) m = fmaxf(m, Crow[l]);
        float ssum = 0.f;
        for (int l = 0; l < LL; l++) ssum += __expf(Crow[l] - m);
        float inv = 1.f / ssum;
        float* Wb = W + (size_t)i * LL * NN;
        for (int l = 0; l < LL; l++)
            Wb[(size_t)l * NN + n] = __expf(Crow[l] - m) * inv;  // coalesced over n
    }
    __syncthreads();

    // S[i][j0+jh] = (sum_n rowred + sum_l colred) / N   (waves 0,1)
    if (tid < NN) {
        int jh = tid >> 6, t = tid & 63;
        float p = rowred[jh * 128 + t] + rowred[jh * 128 + 64 + t] + colred[jh * 64 + t];
#pragma unroll
        for (int off = 32; off; off >>= 1) p += __shfl_down(p, off);
        if (t == 0) S[i * BSZ + j0 + jh] = p / (float)NN;
    }
}

// ---------------------------------------------------------------------------
// Kernel 2: text_emb_i2s[b,n,d] = sum_l W[b][l][n] * img[b][l][d]
// Grid: (64 b, 3 d-chunks of 256, 8 n-groups of 16).  W chunk staged in LDS.
// ---------------------------------------------------------------------------
__global__ __launch_bounds__(256) void k_i2s(
    const float* __restrict__ W, const float* __restrict__ img,
    float* __restrict__ out)
{
    __shared__ float Ws[LL][16];   // 4 KB
    const int b  = blockIdx.x;
    const int ng = blockIdx.z * 16;
    const int d  = blockIdx.y * 256 + threadIdx.x;
    const float* Wb = W + (size_t)b * LL * NN;

    {   // stage W[l][ng..ng+15]: 1024 floats, 4 per thread
        int t4 = threadIdx.x * 4;
        int l = t4 >> 4, noff = t4 & 15;
        float4 w = *(const float4*)(Wb + (size_t)l * NN + ng + noff);
        Ws[l][noff + 0] = w.x; Ws[l][noff + 1] = w.y;
        Ws[l][noff + 2] = w.z; Ws[l][noff + 3] = w.w;
    }
    __syncthreads();

    const float* ib = img + (size_t)b * LL * DD;
    float* ob = out + 1 + (size_t)b * NN * DD + (size_t)ng * DD;  // slot 0 = loss

    float acc[16];
#pragma unroll
    for (int q = 0; q < 16; q++) acc[q] = 0.f;
    for (int l = 0; l < LL; l++) {
        float g = ib[(size_t)l * DD + d];
#pragma unroll
        for (int q = 0; q < 16; q++)
            acc[q] = fmaf(Ws[l][q], g, acc[q]);   // Ws read is broadcast
    }
#pragma unroll
    for (int q = 0; q < 16; q++)
        ob[(size_t)q * DD + d] = acc[q];
}

// ---------------------------------------------------------------------------
// Kernel 3: loss = -sum_i( 2*S[i,i] - lse_row_i(S) - lse_col_i(S) ) / B
// ---------------------------------------------------------------------------
__global__ void k_loss(const float* __restrict__ S, float* __restrict__ out)
{
    const int t = threadIdx.x;  // 0..63
    float diag = S[t * BSZ + t];
    float m1 = -INFINITY, m2 = -INFINITY;
    for (int jj = 0; jj < BSZ; jj++) {
        m1 = fmaxf(m1, S[t * BSZ + jj]);
        m2 = fmaxf(m2, S[jj * BSZ + t]);
    }
    float s1 = 0.f, s2 = 0.f;
    for (int jj = 0; jj < BSZ; jj++) {
        s1 += __expf(S[t * BSZ + jj] - m1);
        s2 += __expf(S[jj * BSZ + t] - m2);
    }
    float p = 2.f * diag - (m1 + logf(s1)) - (m2 + logf(s2));
#pragma unroll
    for (int off = 32; off; off >>= 1) p += __shfl_down(p, off);
    if (t == 0) out[0] = -p / (float)BSZ;
}

// ---------------------------------------------------------------------------
extern "C" void kernel_launch(void* const* d_in, const int* in_sizes, int n_in,
                              void* d_out, int out_size, void* d_ws, size_t ws_size,
                              hipStream_t stream)
{
    (void)in_sizes; (void)n_in; (void)out_size; (void)ws_size;
    const float* text = (const float*)d_in[0];   // [64,128,768] fp32
    const float* img  = (const float*)d_in[1];   // [64, 64,768] fp32
    const int*   tm   = (const int*)d_in[2];     // [64,128] int32
    const int*   im   = (const int*)d_in[3];     // [64, 64] int32
    float* out = (float*)d_out;                  // [1 + 64*128*768] fp32

    // workspace layout (bytes); total ~40 MB
    char* ws = (char*)d_ws;
    unsigned short* Ahi = (unsigned short*)(ws);                       // 12.58 MB
    unsigned short* Alo = (unsigned short*)(ws + 12582912);            // 12.58 MB
    unsigned short* Bhi = (unsigned short*)(ws + 25165824);            //  6.29 MB
    unsigned short* Blo = (unsigned short*)(ws + 31457280);            //  6.29 MB
    float* S = (float*)(ws + 37748736);                                // 16 KB
    float* W = (float*)(ws + 37765120);                                //  2 MB

    k_prep<<<(TQ + IQ) / 256, 256, 0, stream>>>(
        (const float4*)text, (const float4*)img,
        (uint2*)Ahi, (uint2*)Alo, (uint2*)Bhi, (uint2*)Blo);

    k_scores<<<BSZ * (BSZ / 2), 256, 0, stream>>>(Ahi, Alo, Bhi, Blo, tm, im, S, W);

    dim3 g2(BSZ, 3, 8);
    k_i2s<<<g2, 256, 0, stream>>>(W, img, out);

    k_loss<<<1, 64, 0, stream>>>(S, out);
}

// Round 4
// 186.053 us; speedup vs baseline: 4.3195x; 1.5576x over previous
//
#include <hip/hip_runtime.h>
#include <math.h>

// Problem constants (B, N, L, D) from the reference setup_inputs().
#define BSZ 64
#define NN  128
#define LL  64
#define DD  768
#define NEGV (-9e9f)

#define TQ (BSZ * NN * DD / 4)   // text float4 count  = 1572864
#define IQ (BSZ * LL * DD / 4)   // image float4 count =  786432

typedef _Float16 f16x8 __attribute__((ext_vector_type(8)));  // 8 f16 = 4 VGPRs
typedef __attribute__((ext_vector_type(4))) float f32x4;     // MFMA 16x16 accum

// async 16B global -> LDS (dest = wave-uniform base + lane*16)
__device__ __forceinline__ void gl_lds16(const void* g, void* l) {
    __builtin_amdgcn_global_load_lds(
        (const __attribute__((address_space(1))) void*)g,
        (__attribute__((address_space(3))) void*)l, 16, 0, 0);
}

// ---------------------------------------------------------------------------
// Kernel 0: fp32 -> fp16 (RTN). Error 2^-11 relative; N(0,1) inputs, no
// range issues. Single pass replaces the R3 split-bf16 (3x MFMA) scheme.
// ---------------------------------------------------------------------------
__global__ __launch_bounds__(256) void k_prep(
    const float4* __restrict__ t4, const float4* __restrict__ g4,
    ushort4* __restrict__ A, ushort4* __restrict__ B)
{
    int id = blockIdx.x * 256 + threadIdx.x;
    const float4* src; ushort4* dst; int idx;
    if (id < TQ) { src = t4; dst = A; idx = id; }
    else         { src = g4; dst = B; idx = id - TQ; }
    float4 x = src[idx];
    _Float16 h0 = (_Float16)x.x, h1 = (_Float16)x.y;
    _Float16 h2 = (_Float16)x.z, h3 = (_Float16)x.w;
    ushort4 o;
    o.x = __builtin_bit_cast(unsigned short, h0);
    o.y = __builtin_bit_cast(unsigned short, h1);
    o.z = __builtin_bit_cast(unsigned short, h2);
    o.w = __builtin_bit_cast(unsigned short, h3);
    dst[idx] = o;
}

// ---------------------------------------------------------------------------
// Stage one 32 KB chunk (A: 128 rows x 64 k f16, B: 128 rows x 64 k) into LDS.
// LDS slot for (r, k8): r*8 + (k8 ^ (r&7)), 16B per slot (XOR bank swizzle).
// global_load_lds dest = wave-uniform base + lane*16; slot index is linear
// in (call, wave, lane): slot = c*256 + wave*64 + lane.
// ---------------------------------------------------------------------------
__device__ __forceinline__ void stage_chunk(
    const unsigned short* __restrict__ pa, const unsigned short* __restrict__ pb,
    int k0, char* buf, int wave, int lane)
{
    int rsub = lane >> 3;     // 0..7
    int k8s  = lane & 7;
#pragma unroll
    for (int c = 0; c < 4; c++) {
        int r  = c * 32 + wave * 8 + rsub;
        int k8 = k8s ^ (r & 7);
        gl_lds16(pa + (size_t)r * DD + k0 + k8 * 8, buf + c * 4096 + wave * 1024);
        gl_lds16(pb + (size_t)r * DD + k0 + k8 * 8, buf + 16384 + c * 4096 + wave * 1024);
    }
}

// ---------------------------------------------------------------------------
// Kernel 1: one block per (i, jj) where jj covers j = {2jj, 2jj+1}.
// C[128][128] = text[i] @ [image[j0]; image[j1]]^T, single-pass fp16 MFMA,
// LDS-staged via global_load_lds, double-buffered, 12 chunks of BK=64.
// Epilogue: masked softmax reductions (verified), S + diagonal W.
// ---------------------------------------------------------------------------
__global__ __launch_bounds__(256, 2) void k_scores(
    const unsigned short* __restrict__ A, const unsigned short* __restrict__ B,
    const int* __restrict__ tmask, const int* __restrict__ imask,
    float* __restrict__ S, float* __restrict__ W)
{
    union SmemU {
        char  stage[2][32768];     // [buf][A 16KB | B 16KB]
        float Cs[NN][129];         // 66 KB epilogue tile (stride 129: 2-way free)
    };
    __shared__ SmemU u;
    __shared__ float tmi[NN];
    __shared__ float imj[NN];      // 128 cols = two j's
    __shared__ float rowred[256];
    __shared__ float colred[NN];

    // 4x4 block-group swizzle for L2 locality (~1.6 MB working set / group)
    const int bid = blockIdx.x;
    const int grp = bid >> 4, idx = bid & 15;
    const int i  = (grp >> 3) * 4 + (idx >> 2);   // 0..63
    const int jj = (grp & 7) * 4 + (idx & 3);     // 0..31
    const int j0 = jj * 2;

    const int tid  = threadIdx.x;
    const int wave = tid >> 6;
    const int lane = tid & 63;
    const int quad = lane >> 4;
    const int l15  = lane & 15;
    const int rh   = wave & 1;     // row half (64 rows)
    const int ch   = wave >> 1;    // col half (64 cols)

    if (tid < NN) {
        tmi[tid] = tmask[i * NN + tid] ? 1.f : 0.f;
        imj[tid] = imask[j0 * LL + tid] ? 1.f : 0.f;   // two j's contiguous
    }

    const unsigned short* pa = A + (size_t)i * NN * DD;
    const unsigned short* pb = B + (size_t)j0 * LL * DD;

    f32x4 acc[4][4];
    const f32x4 zf = {0.f, 0.f, 0.f, 0.f};
#pragma unroll
    for (int tr = 0; tr < 4; tr++)
#pragma unroll
        for (int tc = 0; tc < 4; tc++) acc[tr][tc] = zf;

    stage_chunk(pa, pb, 0, u.stage[0], wave, lane);
    __syncthreads();

    for (int c = 0; c < 12; c++) {
        if (c + 1 < 12)
            stage_chunk(pa, pb, (c + 1) << 6, u.stage[(c + 1) & 1], wave, lane);
        const char* Ab = u.stage[c & 1];
        const char* Bb = Ab + 16384;
#pragma unroll
        for (int s = 0; s < 2; s++) {
            int k8q = s * 4 + quad;
            int sw  = k8q ^ (l15 & 7);
            f16x8 af[4], bfr[4];
#pragma unroll
            for (int t = 0; t < 4; t++) {
                int row = rh * 64 + t * 16 + l15;
                af[t]  = *(const f16x8*)(Ab + ((row << 3) + sw) * 16);
                int col = ch * 64 + t * 16 + l15;
                bfr[t] = *(const f16x8*)(Bb + ((col << 3) + sw) * 16);
            }
#pragma unroll
            for (int tr = 0; tr < 4; tr++)
#pragma unroll
                for (int tc = 0; tc < 4; tc++)
                    acc[tr][tc] = __builtin_amdgcn_mfma_f32_16x16x32_f16(
                        af[tr], bfr[tc], acc[tr][tc], 0, 0, 0);
        }
        __syncthreads();
    }

    // masked att -> Cs.  att = (mask && dot != 0) ? dot : NEG
    // C/D layout per 16x16 tile: row = quad*4 + rr, col = l15
#pragma unroll
    for (int tr = 0; tr < 4; tr++) {
        int rb = rh * 64 + tr * 16 + quad * 4;
#pragma unroll
        for (int tc = 0; tc < 4; tc++) {
            int col = ch * 64 + tc * 16 + l15;
            float im = imj[col];
#pragma unroll
            for (int rr = 0; rr < 4; rr++) {
                int row = rb + rr;
                float v = acc[tr][tc][rr];
                bool keep = (tmi[row] != 0.f) && (im != 0.f) && (v != 0.f);
                u.Cs[row][col] = keep ? v : NEGV;
            }
        }
    }
    __syncthreads();

    // phase 1: row softmax over l for each (jh, n) -- all 256 threads
    {
        int jh = tid >> 7, n = tid & 127;
        const float* Crow = &u.Cs[n][jh * 64];
        float m = -INFINITY;
        for (int l = 0; l < LL; l++) m = fmaxf(m, Crow[l]);
        float ssum = 0.f, ws = 0.f;
        for (int l = 0; l < LL; l++) {
            float v = Crow[l];
            float e = __expf(v - m);      // all-NEG row -> uniform
            ssum += e;
            ws += imj[jh * 64 + l] * e * v;
        }
        rowred[tid] = tmi[n] * (ws / ssum);
    }
    __syncthreads();

    // phase 2: threads 0..127 col softmax; threads 128..255 diagonal W
    if (tid < NN) {
        int jh = tid >> 6, l = tid & 63;
        float m = -INFINITY;
        for (int n = 0; n < NN; n++) m = fmaxf(m, u.Cs[n][jh * 64 + l]);
        float ssum = 0.f, ws = 0.f;
        for (int n = 0; n < NN; n++) {
            float v = u.Cs[n][jh * 64 + l];
            float e = __expf(v - m);
            ssum += e;
            ws += tmi[n] * e * v;
        }
        colred[tid] = imj[jh * 64 + l] * (ws / ssum);
    } else if (jj == (i >> 1)) {
        // this block holds the diagonal pair j == i at half jh = i & 1
        int jh = i & 1;
        int n = tid & 127;
        const float* Crow = &u.Cs[n][jh * 64];
        float m = -INFINITY;
        for (int l = 0; l < LL; l++) m = fmaxf(m, Crow[l]);
        float ssum = 0.f;
        for (int l = 0; l < LL; l++) ssum += __expf(Crow[l] - m);
        float inv = 1.f / ssum;
        float* Wb = W + (size_t)i * LL * NN;
        for (int l = 0; l < LL; l++)
            Wb[(size_t)l * NN + n] = __expf(Crow[l] - m) * inv;  // coalesced over n
    }
    __syncthreads();

    // S[i][j0+jh] = (sum_n rowred + sum_l colred) / N   (waves 0,1)
    if (tid < NN) {
        int jh = tid >> 6, t = tid & 63;
        float p = rowred[jh * 128 + t] + rowred[jh * 128 + 64 + t] + colred[jh * 64 + t];
#pragma unroll
        for (int off = 32; off; off >>= 1) p += __shfl_down(p, off);
        if (t == 0) S[i * BSZ + j0 + jh] = p / (float)NN;
    }
}

// ---------------------------------------------------------------------------
// Kernel 2: text_emb_i2s[b,n,d] = sum_l W[b][l][n] * img[b][l][d]
// Grid: (64 b, 3 d-chunks of 256, 8 n-groups of 16).  W chunk staged in LDS.
// ---------------------------------------------------------------------------
__global__ __launch_bounds__(256) void k_i2s(
    const float* __restrict__ W, const float* __restrict__ img,
    float* __restrict__ out)
{
    __shared__ float Ws[LL][16];   // 4 KB
    const int b  = blockIdx.x;
    const int ng = blockIdx.z * 16;
    const int d  = blockIdx.y * 256 + threadIdx.x;
    const float* Wb = W + (size_t)b * LL * NN;

    {   // stage W[l][ng..ng+15]: 1024 floats, 4 per thread
        int t4 = threadIdx.x * 4;
        int l = t4 >> 4, noff = t4 & 15;
        float4 w = *(const float4*)(Wb + (size_t)l * NN + ng + noff);
        Ws[l][noff + 0] = w.x; Ws[l][noff + 1] = w.y;
        Ws[l][noff + 2] = w.z; Ws[l][noff + 3] = w.w;
    }
    __syncthreads();

    const float* ib = img + (size_t)b * LL * DD;
    float* ob = out + 1 + (size_t)b * NN * DD + (size_t)ng * DD;  // slot 0 = loss

    float acc[16];
#pragma unroll
    for (int q = 0; q < 16; q++) acc[q] = 0.f;
    for (int l = 0; l < LL; l++) {
        float g = ib[(size_t)l * DD + d];
#pragma unroll
        for (int q = 0; q < 16; q++)
            acc[q] = fmaf(Ws[l][q], g, acc[q]);   // Ws read is broadcast
    }
#pragma unroll
    for (int q = 0; q < 16; q++)
        ob[(size_t)q * DD + d] = acc[q];
}

// ---------------------------------------------------------------------------
// Kernel 3: loss = -sum_i( 2*S[i,i] - lse_row_i(S) - lse_col_i(S) ) / B
// ---------------------------------------------------------------------------
__global__ void k_loss(const float* __restrict__ S, float* __restrict__ out)
{
    const int t = threadIdx.x;  // 0..63
    float diag = S[t * BSZ + t];
    float m1 = -INFINITY, m2 = -INFINITY;
    for (int jj = 0; jj < BSZ; jj++) {
        m1 = fmaxf(m1, S[t * BSZ + jj]);
        m2 = fmaxf(m2, S[jj * BSZ + t]);
    }
    float s1 = 0.f, s2 = 0.f;
    for (int jj = 0; jj < BSZ; jj++) {
        s1 += __expf(S[t * BSZ + jj] - m1);
        s2 += __expf(S[jj * BSZ + t] - m2);
    }
    float p = 2.f * diag - (m1 + logf(s1)) - (m2 + logf(s2));
#pragma unroll
    for (int off = 32; off; off >>= 1) p += __shfl_down(p, off);
    if (t == 0) out[0] = -p / (float)BSZ;
}

// ---------------------------------------------------------------------------
extern "C" void kernel_launch(void* const* d_in, const int* in_sizes, int n_in,
                              void* d_out, int out_size, void* d_ws, size_t ws_size,
                              hipStream_t stream)
{
    (void)in_sizes; (void)n_in; (void)out_size; (void)ws_size;
    const float* text = (const float*)d_in[0];   // [64,128,768] fp32
    const float* img  = (const float*)d_in[1];   // [64, 64,768] fp32
    const int*   tm   = (const int*)d_in[2];     // [64,128] int32
    const int*   im   = (const int*)d_in[3];     // [64, 64] int32
    float* out = (float*)d_out;                  // [1 + 64*128*768] fp32

    // workspace layout (bytes); total ~21 MB
    char* ws = (char*)d_ws;
    unsigned short* A = (unsigned short*)(ws);                   // 12.58 MB fp16
    unsigned short* B = (unsigned short*)(ws + 12582912);        //  6.29 MB fp16
    float* S = (float*)(ws + 18874368);                          // 16 KB
    float* W = (float*)(ws + 18890752);                          //  2 MB

    k_prep<<<(TQ + IQ) / 256, 256, 0, stream>>>(
        (const float4*)text, (const float4*)img, (ushort4*)A, (ushort4*)B);

    k_scores<<<BSZ * (BSZ / 2), 256, 0, stream>>>(A, B, tm, im, S, W);

    dim3 g2(BSZ, 3, 8);
    k_i2s<<<g2, 256, 0, stream>>>(W, img, out);

    k_loss<<<1, 64, 0, stream>>>(S, out);
}